// Round 3
// baseline (196.933 us; speedup 1.0000x reference)
//
#include <hip/hip_runtime.h>
#include <hip/hip_bf16.h>

#define T_ROWS 8192
#define K_DIM  1024
#define N_DIM  2048
#define G_NUM  8
#define CONVA_BLOCKS 4096   // (T*K/8)/256
#define CONVB_BLOCKS 4096   // G*(K/64)*(N/64)

typedef __attribute__((ext_vector_type(8))) short short8;
typedef __attribute__((ext_vector_type(4))) float v4f;

// ---------- helpers ----------
__device__ __forceinline__ unsigned short f2bf(float x) {
  unsigned int u = __builtin_bit_cast(unsigned int, x);
  u += 0x7fffu + ((u >> 16) & 1u);   // round-to-nearest-even
  return (unsigned short)(u >> 16);
}
__device__ __forceinline__ unsigned int pk2(float a, float b) {
  return (unsigned int)f2bf(a) | ((unsigned int)f2bf(b) << 16);
}
__device__ __forceinline__ void async_cp16(const void* gsrc, void* ldst) {
  __builtin_amdgcn_global_load_lds(
      (const __attribute__((address_space(1))) void*)gsrc,
      (__attribute__((address_space(3))) void*)ldst, 16, 0, 0);
}

// ---------- fused convert: blocks [0,4096) do A, [4096,8192) do B-transpose ----------
__global__ __launch_bounds__(256) void conv_fused(const float* __restrict__ A,
                                                  const float* __restrict__ B,
                                                  unsigned short* __restrict__ Ab,
                                                  unsigned short* __restrict__ Bt) {
  __shared__ float tile[64][65];   // only used by the B path; +1 pad -> conflict-free
  int bid = blockIdx.x;
  const int t = threadIdx.x;

  if (bid < CONVA_BLOCKS) {
    // ---- A fp32 -> bf16, same layout, 8 floats/thread ----
    size_t idx = (size_t)bid * 256 + t;
    const float4* src = (const float4*)A;
    float4 v0 = src[idx * 2], v1 = src[idx * 2 + 1];
    uint4 o;
    o.x = pk2(v0.x, v0.y); o.y = pk2(v0.z, v0.w);
    o.z = pk2(v1.x, v1.y); o.w = pk2(v1.z, v1.w);
    ((uint4*)Ab)[idx] = o;
    return;
  }
  bid -= CONVA_BLOCKS;
  // ---- B[g][k][n] fp32 -> Bt[g][n][k] bf16 via padded-LDS 64x64 transpose ----
  const int nt = bid & 31;          // N/64
  const int kt = (bid >> 5) & 15;   // K/64
  const int g  = bid >> 9;          // G
  const int c4 = t & 15;
  const int r  = t >> 4;

  const float* src = B + ((size_t)g * K_DIM + (size_t)kt * 64) * N_DIM + (size_t)nt * 64;
#pragma unroll
  for (int i = 0; i < 4; ++i) {
    int k = r + i * 16;
    float4 v = *(const float4*)(src + (size_t)k * N_DIM + c4 * 4);
    tile[k][c4 * 4 + 0] = v.x; tile[k][c4 * 4 + 1] = v.y;
    tile[k][c4 * 4 + 2] = v.z; tile[k][c4 * 4 + 3] = v.w;
  }
  __syncthreads();
  unsigned short* dst = Bt + ((size_t)g * N_DIM + (size_t)nt * 64) * K_DIM + (size_t)kt * 64;
#pragma unroll
  for (int i = 0; i < 2; ++i) {
    int idx = t + i * 256;
    int n = idx >> 3;
    int seg = idx & 7;
    unsigned int u0 = pk2(tile[seg * 8 + 0][n], tile[seg * 8 + 1][n]);
    unsigned int u1 = pk2(tile[seg * 8 + 2][n], tile[seg * 8 + 3][n]);
    unsigned int u2 = pk2(tile[seg * 8 + 4][n], tile[seg * 8 + 5][n]);
    unsigned int u3 = pk2(tile[seg * 8 + 6][n], tile[seg * 8 + 7][n]);
    uint4 o; o.x = u0; o.y = u1; o.z = u2; o.w = u3;
    *(uint4*)(dst + (size_t)n * K_DIM + seg * 8) = o;
  }
}

// ---------- grouped bf16 MFMA GEMM, 128x128 tile, BK=64, double-buffered LDS ----------
// Single barrier per k-iter: the top barrier's vmcnt(0) drain makes buf[p]
// ready AND proves all waves finished reading buf[p^1]; next-tile loads into
// buf[p^1] then fly across the entire compute phase (in-wave overlap the
// previous 2-barrier structure could not express).
__global__ __launch_bounds__(256) void gemm_kernel(const unsigned short* __restrict__ Ab,
                                                   const unsigned short* __restrict__ Btb,
                                                   const int* __restrict__ offs,
                                                   float* __restrict__ out) {
  __shared__ unsigned short As[2][128 * 64];
  __shared__ unsigned short Bs[2][128 * 64];
  const int t = threadIdx.x;
  const int n0 = blockIdx.x * 128;
  const int mslot = blockIdx.y;

  // slot -> (group, row tile); wave-uniform
  int prev = 0, cum = 0, row0 = 0, row_end = 0, g = 0, found = 0;
#pragma unroll
  for (int gg = 0; gg < G_NUM; ++gg) {
    int e = offs[gg];
    int tiles = (e - prev + 127) >> 7;
    if (!found && mslot < cum + tiles) {
      found = 1; g = gg; row0 = prev + (mslot - cum) * 128; row_end = e;
    }
    cum += tiles;
    prev = e;
  }
  if (!found) return;

  const int lane = t & 63;
  const int wv = t >> 6;
  const int wm = wv & 1;
  const int wn = wv >> 1;
  const int srcChunk = (t & 7) ^ ((t >> 3) & 7);  // XOR swizzle, matches frag-read side

  // hoisted global source pointers (k0-invariant)
  const unsigned short* aSrc[4];
  const unsigned short* bSrc[4];
#pragma unroll
  for (int c = 0; c < 4; ++c) {
    int rl = c * 32 + (t >> 3);
    int rA = row0 + rl; if (rA > T_ROWS - 1) rA = T_ROWS - 1;  // tail clamp (store-masked)
    aSrc[c] = Ab + (size_t)rA * K_DIM + srcChunk * 8;
    bSrc[c] = Btb + ((size_t)g * N_DIM + n0 + rl) * K_DIM + srcChunk * 8;
  }

  v4f acc[4][4];
#pragma unroll
  for (int i = 0; i < 4; ++i)
#pragma unroll
    for (int j = 0; j < 4; ++j)
#pragma unroll
      for (int r = 0; r < 4; ++r) acc[i][j][r] = 0.0f;

  // peel: prefetch k0 = 0 into buffer 0
#pragma unroll
  for (int c = 0; c < 4; ++c) {
    async_cp16(aSrc[c], (char*)&As[0][0] + c * 4096 + t * 16);
    async_cp16(bSrc[c], (char*)&Bs[0][0] + c * 4096 + t * 16);
  }

  int p = 0;
  for (int k0 = 0; k0 < K_DIM; k0 += 64) {
    __syncthreads();   // drains vmcnt(0): buf[p] ready; buf[p^1] free to overwrite
    if (k0 + 64 < K_DIM) {
      int koff = k0 + 64;
      int q = p ^ 1;
#pragma unroll
      for (int c = 0; c < 4; ++c) {
        async_cp16(aSrc[c] + koff, (char*)&As[q][0] + c * 4096 + t * 16);
        async_cp16(bSrc[c] + koff, (char*)&Bs[q][0] + c * 4096 + t * 16);
      }
    }
    const char* aBase = (const char*)&As[p][0];
    const char* bBase = (const char*)&Bs[p][0];
#pragma unroll
    for (int ks = 0; ks < 2; ++ks) {
      short8 a[4], b[4];
      int chBase = (lane >> 4) + ks * 4;
      int chPhys = chBase ^ (lane & 7);
#pragma unroll
      for (int im = 0; im < 4; ++im) {
        int row = wm * 64 + im * 16 + (lane & 15);
        a[im] = *(const short8*)(aBase + row * 128 + chPhys * 16);
      }
#pragma unroll
      for (int in = 0; in < 4; ++in) {
        int row = wn * 64 + in * 16 + (lane & 15);
        b[in] = *(const short8*)(bBase + row * 128 + chPhys * 16);
      }
#pragma unroll
      for (int im = 0; im < 4; ++im)
#pragma unroll
        for (int in = 0; in < 4; ++in)
          acc[im][in] = __builtin_amdgcn_mfma_f32_16x16x32_bf16(a[im], b[in], acc[im][in], 0, 0, 0);
    }
    p ^= 1;
  }

  // epilogue: C/D layout col=lane&15, row=(lane>>4)*4+reg
  const int colBase = n0 + wn * 64 + (lane & 15);
  const int rowBase = row0 + wm * 64 + ((lane >> 4) << 2);
#pragma unroll
  for (int im = 0; im < 4; ++im) {
#pragma unroll
    for (int in = 0; in < 4; ++in) {
      int c = colBase + in * 16;
#pragma unroll
      for (int r = 0; r < 4; ++r) {
        int rr = rowBase + im * 16 + r;
        if (rr < row_end) out[(size_t)rr * N_DIM + c] = acc[im][in][r];
      }
    }
  }
}

// ---------- fallback (workspace too small): fp32 vector GEMM ----------
__global__ __launch_bounds__(256) void fallback_kernel(const float* __restrict__ A,
                                                       const float* __restrict__ B,
                                                       const int* __restrict__ offs,
                                                       float* __restrict__ out) {
  int r = blockIdx.y;
  int c = blockIdx.x * 256 + threadIdx.x;
  int g = 0;
#pragma unroll
  for (int i = 0; i < G_NUM; ++i) g += (offs[i] <= r);
  const float* a = A + (size_t)r * K_DIM;
  const float* b = B + (size_t)g * K_DIM * N_DIM + c;
  float s = 0.f;
  for (int k = 0; k < K_DIM; ++k) s += a[k] * b[(size_t)k * N_DIM];
  out[(size_t)r * N_DIM + c] = s;
}

extern "C" void kernel_launch(void* const* d_in, const int* in_sizes, int n_in,
                              void* d_out, int out_size, void* d_ws, size_t ws_size,
                              hipStream_t stream) {
  const float* A = (const float*)d_in[0];
  const float* B = (const float*)d_in[1];
  const int* offs = (const int*)d_in[2];
  float* out = (float*)d_out;

  size_t need = ((size_t)T_ROWS * K_DIM + (size_t)G_NUM * K_DIM * N_DIM) * 2;
  if (ws_size < need) {
    dim3 grid(N_DIM / 256, T_ROWS);
    fallback_kernel<<<grid, 256, 0, stream>>>(A, B, offs, out);
    return;
  }
  unsigned short* Ab = (unsigned short*)d_ws;
  unsigned short* Btb = Ab + (size_t)T_ROWS * K_DIM;

  conv_fused<<<CONVA_BLOCKS + CONVB_BLOCKS, 256, 0, stream>>>(A, B, Ab, Btb);
  dim3 grid(N_DIM / 128, T_ROWS / 128 + G_NUM);
  gemm_kernel<<<grid, 256, 0, stream>>>(Ab, Btb, offs, out);
}

// Round 4
// 191.595 us; speedup vs baseline: 1.0279x; 1.0279x over previous
//
#include <hip/hip_runtime.h>
#include <hip/hip_bf16.h>

#define T_ROWS 8192
#define K_DIM  1024
#define N_DIM  2048
#define G_NUM  8
#define CONVA_BLOCKS 2048   // (T*K/16)/256 -- 16 floats per thread
#define CONVB_BLOCKS 4096   // G*(K/64)*(N/64)

typedef __attribute__((ext_vector_type(8))) short short8;
typedef __attribute__((ext_vector_type(4))) float v4f;

// ---------- helpers ----------
__device__ __forceinline__ unsigned short f2bf(float x) {
  unsigned int u = __builtin_bit_cast(unsigned int, x);
  u += 0x7fffu + ((u >> 16) & 1u);   // round-to-nearest-even
  return (unsigned short)(u >> 16);
}
__device__ __forceinline__ unsigned int pk2(float a, float b) {
  return (unsigned int)f2bf(a) | ((unsigned int)f2bf(b) << 16);
}
__device__ __forceinline__ void async_cp16(const void* gsrc, void* ldst) {
  __builtin_amdgcn_global_load_lds(
      (const __attribute__((address_space(1))) void*)gsrc,
      (__attribute__((address_space(3))) void*)ldst, 16, 0, 0);
}

// ---------- fused convert, INTERLEAVED: bid%3==0 -> A-stream, else B-transpose ----
// Interleaving mixes pure-streaming (A) and LDS-transpose (B) blocks on every
// CU throughout the dispatch instead of phase-separating them, keeping HBM
// saturated while B blocks sit in their LDS/barrier phase.
__global__ __launch_bounds__(256) void conv_fused(const float* __restrict__ A,
                                                  const float* __restrict__ B,
                                                  unsigned short* __restrict__ Ab,
                                                  unsigned short* __restrict__ Bt) {
  __shared__ float tile[64][65];   // B path only; +1 pad -> conflict-free
  const int bid = blockIdx.x;
  const int t = threadIdx.x;
  const int q3 = bid / 3, r3 = bid - q3 * 3;

  if (r3 == 0) {
    // ---- A fp32 -> bf16, same layout, 16 floats/thread ----
    size_t idx = (size_t)q3 * 256 + t;          // [0, 2048*256)
    const float4* src = (const float4*)A + idx * 4;
    float4 v0 = src[0], v1 = src[1], v2 = src[2], v3 = src[3];
    uint4 o0, o1;
    o0.x = pk2(v0.x, v0.y); o0.y = pk2(v0.z, v0.w);
    o0.z = pk2(v1.x, v1.y); o0.w = pk2(v1.z, v1.w);
    o1.x = pk2(v2.x, v2.y); o1.y = pk2(v2.z, v2.w);
    o1.z = pk2(v3.x, v3.y); o1.w = pk2(v3.z, v3.w);
    ((uint4*)Ab)[idx * 2]     = o0;
    ((uint4*)Ab)[idx * 2 + 1] = o1;
    return;
  }
  // ---- B[g][k][n] fp32 -> Bt[g][n][k] bf16 via padded-LDS 64x64 transpose ----
  const int bidx = 2 * q3 + (r3 - 1);           // [0, 4096)
  const int nt = bidx & 31;          // N/64
  const int kt = (bidx >> 5) & 15;   // K/64
  const int g  = bidx >> 9;          // G
  const int c4 = t & 15;
  const int r  = t >> 4;

  const float* src = B + ((size_t)g * K_DIM + (size_t)kt * 64) * N_DIM + (size_t)nt * 64;
#pragma unroll
  for (int i = 0; i < 4; ++i) {
    int k = r + i * 16;
    float4 v = *(const float4*)(src + (size_t)k * N_DIM + c4 * 4);
    tile[k][c4 * 4 + 0] = v.x; tile[k][c4 * 4 + 1] = v.y;
    tile[k][c4 * 4 + 2] = v.z; tile[k][c4 * 4 + 3] = v.w;
  }
  __syncthreads();
  unsigned short* dst = Bt + ((size_t)g * N_DIM + (size_t)nt * 64) * K_DIM + (size_t)kt * 64;
#pragma unroll
  for (int i = 0; i < 2; ++i) {
    int idx = t + i * 256;
    int n = idx >> 3;
    int seg = idx & 7;
    unsigned int u0 = pk2(tile[seg * 8 + 0][n], tile[seg * 8 + 1][n]);
    unsigned int u1 = pk2(tile[seg * 8 + 2][n], tile[seg * 8 + 3][n]);
    unsigned int u2 = pk2(tile[seg * 8 + 4][n], tile[seg * 8 + 5][n]);
    unsigned int u3 = pk2(tile[seg * 8 + 6][n], tile[seg * 8 + 7][n]);
    uint4 o; o.x = u0; o.y = u1; o.z = u2; o.w = u3;
    *(uint4*)(dst + (size_t)n * K_DIM + seg * 8) = o;
  }
}

// ---------- grouped bf16 MFMA GEMM, 128x128 tile, BK=64 (R2 structure) ----------
// Single 32 KB LDS buffer, two barriers per k-iter, hoisted k0-invariant
// pointers, peeled first prefetch. Proven 55.7-60.8 us; explicit double-buffer
// (R3) regressed via occupancy loss -- do not reintroduce.
__global__ __launch_bounds__(256) void gemm_kernel(const unsigned short* __restrict__ Ab,
                                                   const unsigned short* __restrict__ Btb,
                                                   const int* __restrict__ offs,
                                                   float* __restrict__ out) {
  __shared__ unsigned short As[128 * 64];
  __shared__ unsigned short Bs[128 * 64];
  const int t = threadIdx.x;
  const int n0 = blockIdx.x * 128;
  const int mslot = blockIdx.y;

  // slot -> (group, row tile); wave-uniform
  int prev = 0, cum = 0, row0 = 0, row_end = 0, g = 0, found = 0;
#pragma unroll
  for (int gg = 0; gg < G_NUM; ++gg) {
    int e = offs[gg];
    int tiles = (e - prev + 127) >> 7;
    if (!found && mslot < cum + tiles) {
      found = 1; g = gg; row0 = prev + (mslot - cum) * 128; row_end = e;
    }
    cum += tiles;
    prev = e;
  }
  if (!found) return;

  const int lane = t & 63;
  const int wv = t >> 6;
  const int wm = wv & 1;
  const int wn = wv >> 1;
  const int srcChunk = (t & 7) ^ ((t >> 3) & 7);  // XOR swizzle, matches frag-read side

  // hoisted global source pointers (k0-invariant) and LDS destinations
  const unsigned short* aSrc[4];
  const unsigned short* bSrc[4];
  char* aDst[4];
  char* bDst[4];
#pragma unroll
  for (int c = 0; c < 4; ++c) {
    int rl = c * 32 + (t >> 3);
    int rA = row0 + rl; if (rA > T_ROWS - 1) rA = T_ROWS - 1;  // tail clamp (store-masked)
    aSrc[c] = Ab + (size_t)rA * K_DIM + srcChunk * 8;
    bSrc[c] = Btb + ((size_t)g * N_DIM + n0 + rl) * K_DIM + srcChunk * 8;
    aDst[c] = (char*)As + c * 4096 + t * 16;
    bDst[c] = (char*)Bs + c * 4096 + t * 16;
  }

  v4f acc[4][4];
#pragma unroll
  for (int i = 0; i < 4; ++i)
#pragma unroll
    for (int j = 0; j < 4; ++j)
#pragma unroll
      for (int r = 0; r < 4; ++r) acc[i][j][r] = 0.0f;

  // peel: prefetch k0 = 0
#pragma unroll
  for (int c = 0; c < 4; ++c) {
    async_cp16(aSrc[c], aDst[c]);
    async_cp16(bSrc[c], bDst[c]);
  }

  for (int k0 = 0; k0 < K_DIM; k0 += 64) {
    __syncthreads();   // vmcnt(0) drain -> LDS tile ready
#pragma unroll
    for (int ks = 0; ks < 2; ++ks) {
      short8 a[4], b[4];
      int chBase = (lane >> 4) + ks * 4;
      int chPhys = chBase ^ (lane & 7);
#pragma unroll
      for (int im = 0; im < 4; ++im) {
        int row = wm * 64 + im * 16 + (lane & 15);
        a[im] = *(const short8*)((const char*)As + row * 128 + chPhys * 16);
      }
#pragma unroll
      for (int in = 0; in < 4; ++in) {
        int row = wn * 64 + in * 16 + (lane & 15);
        b[in] = *(const short8*)((const char*)Bs + row * 128 + chPhys * 16);
      }
#pragma unroll
      for (int im = 0; im < 4; ++im)
#pragma unroll
        for (int in = 0; in < 4; ++in)
          acc[im][in] = __builtin_amdgcn_mfma_f32_16x16x32_bf16(a[im], b[in], acc[im][in], 0, 0, 0);
    }
    if (k0 + 64 < K_DIM) {
      __syncthreads();   // all waves done reading LDS
      int koff = k0 + 64;
#pragma unroll
      for (int c = 0; c < 4; ++c) {
        async_cp16(aSrc[c] + koff, aDst[c]);
        async_cp16(bSrc[c] + koff, bDst[c]);
      }
    }
  }

  // epilogue: C/D layout col=lane&15, row=(lane>>4)*4+reg
  const int colBase = n0 + wn * 64 + (lane & 15);
  const int rowBase = row0 + wm * 64 + ((lane >> 4) << 2);
#pragma unroll
  for (int im = 0; im < 4; ++im) {
#pragma unroll
    for (int in = 0; in < 4; ++in) {
      int c = colBase + in * 16;
#pragma unroll
      for (int r = 0; r < 4; ++r) {
        int rr = rowBase + im * 16 + r;
        if (rr < row_end) out[(size_t)rr * N_DIM + c] = acc[im][in][r];
      }
    }
  }
}

// ---------- fallback (workspace too small): fp32 vector GEMM ----------
__global__ __launch_bounds__(256) void fallback_kernel(const float* __restrict__ A,
                                                       const float* __restrict__ B,
                                                       const int* __restrict__ offs,
                                                       float* __restrict__ out) {
  int r = blockIdx.y;
  int c = blockIdx.x * 256 + threadIdx.x;
  int g = 0;
#pragma unroll
  for (int i = 0; i < G_NUM; ++i) g += (offs[i] <= r);
  const float* a = A + (size_t)r * K_DIM;
  const float* b = B + (size_t)g * K_DIM * N_DIM + c;
  float s = 0.f;
  for (int k = 0; k < K_DIM; ++k) s += a[k] * b[(size_t)k * N_DIM];
  out[(size_t)r * N_DIM + c] = s;
}

extern "C" void kernel_launch(void* const* d_in, const int* in_sizes, int n_in,
                              void* d_out, int out_size, void* d_ws, size_t ws_size,
                              hipStream_t stream) {
  const float* A = (const float*)d_in[0];
  const float* B = (const float*)d_in[1];
  const int* offs = (const int*)d_in[2];
  float* out = (float*)d_out;

  size_t need = ((size_t)T_ROWS * K_DIM + (size_t)G_NUM * K_DIM * N_DIM) * 2;
  if (ws_size < need) {
    dim3 grid(N_DIM / 256, T_ROWS);
    fallback_kernel<<<grid, 256, 0, stream>>>(A, B, offs, out);
    return;
  }
  unsigned short* Ab = (unsigned short*)d_ws;
  unsigned short* Btb = Ab + (size_t)T_ROWS * K_DIM;

  conv_fused<<<CONVA_BLOCKS + CONVB_BLOCKS, 256, 0, stream>>>(A, B, Ab, Btb);
  dim3 grid(N_DIM / 128, T_ROWS / 128 + G_NUM);
  gemm_kernel<<<grid, 256, 0, stream>>>(Ab, Btb, offs, out);
}

// Round 5
// 185.364 us; speedup vs baseline: 1.0624x; 1.0336x over previous
//
#include <hip/hip_runtime.h>
#include <hip/hip_bf16.h>

#define T_ROWS 8192
#define K_DIM  1024
#define N_DIM  2048
#define G_NUM  8
#define CONVA_BLOCKS 2048   // (T*K/16)/256 -- 16 floats per thread
#define CONVB_BLOCKS 4096   // G*(K/64)*(N/64)

typedef __attribute__((ext_vector_type(8))) short short8;
typedef __attribute__((ext_vector_type(4))) float v4f;

// ---------- helpers ----------
__device__ __forceinline__ unsigned short f2bf(float x) {
  unsigned int u = __builtin_bit_cast(unsigned int, x);
  u += 0x7fffu + ((u >> 16) & 1u);   // round-to-nearest-even
  return (unsigned short)(u >> 16);
}
__device__ __forceinline__ unsigned int pk2(float a, float b) {
  return (unsigned int)f2bf(a) | ((unsigned int)f2bf(b) << 16);
}
__device__ __forceinline__ void async_cp16(const void* gsrc, void* ldst) {
  __builtin_amdgcn_global_load_lds(
      (const __attribute__((address_space(1))) void*)gsrc,
      (__attribute__((address_space(3))) void*)ldst, 16, 0, 0);
}

// ---------- fused convert, INTERLEAVED: bid%3==0 -> A-stream, else B-transpose ----
__global__ __launch_bounds__(256) void conv_fused(const float* __restrict__ A,
                                                  const float* __restrict__ B,
                                                  unsigned short* __restrict__ Ab,
                                                  unsigned short* __restrict__ Bt) {
  __shared__ float tile[64][65];   // B path only; +1 pad -> conflict-free
  const int bid = blockIdx.x;
  const int t = threadIdx.x;
  const int q3 = bid / 3, r3 = bid - q3 * 3;

  if (r3 == 0) {
    // ---- A fp32 -> bf16, same layout, 16 floats/thread ----
    size_t idx = (size_t)q3 * 256 + t;          // [0, 2048*256)
    const float4* src = (const float4*)A + idx * 4;
    float4 v0 = src[0], v1 = src[1], v2 = src[2], v3 = src[3];
    uint4 o0, o1;
    o0.x = pk2(v0.x, v0.y); o0.y = pk2(v0.z, v0.w);
    o0.z = pk2(v1.x, v1.y); o0.w = pk2(v1.z, v1.w);
    o1.x = pk2(v2.x, v2.y); o1.y = pk2(v2.z, v2.w);
    o1.z = pk2(v3.x, v3.y); o1.w = pk2(v3.z, v3.w);
    ((uint4*)Ab)[idx * 2]     = o0;
    ((uint4*)Ab)[idx * 2 + 1] = o1;
    return;
  }
  // ---- B[g][k][n] fp32 -> Bt[g][n][k] bf16 via padded-LDS 64x64 transpose ----
  const int bidx = 2 * q3 + (r3 - 1);           // [0, 4096)
  const int nt = bidx & 31;          // N/64
  const int kt = (bidx >> 5) & 15;   // K/64
  const int g  = bidx >> 9;          // G
  const int c4 = t & 15;
  const int r  = t >> 4;

  const float* src = B + ((size_t)g * K_DIM + (size_t)kt * 64) * N_DIM + (size_t)nt * 64;
#pragma unroll
  for (int i = 0; i < 4; ++i) {
    int k = r + i * 16;
    float4 v = *(const float4*)(src + (size_t)k * N_DIM + c4 * 4);
    tile[k][c4 * 4 + 0] = v.x; tile[k][c4 * 4 + 1] = v.y;
    tile[k][c4 * 4 + 2] = v.z; tile[k][c4 * 4 + 3] = v.w;
  }
  __syncthreads();
  unsigned short* dst = Bt + ((size_t)g * N_DIM + (size_t)nt * 64) * K_DIM + (size_t)kt * 64;
#pragma unroll
  for (int i = 0; i < 2; ++i) {
    int idx = t + i * 256;
    int n = idx >> 3;
    int seg = idx & 7;
    unsigned int u0 = pk2(tile[seg * 8 + 0][n], tile[seg * 8 + 1][n]);
    unsigned int u1 = pk2(tile[seg * 8 + 2][n], tile[seg * 8 + 3][n]);
    unsigned int u2 = pk2(tile[seg * 8 + 4][n], tile[seg * 8 + 5][n]);
    unsigned int u3 = pk2(tile[seg * 8 + 6][n], tile[seg * 8 + 7][n]);
    uint4 o; o.x = u0; o.y = u1; o.z = u2; o.w = u3;
    *(uint4*)(dst + (size_t)n * K_DIM + seg * 8) = o;
  }
}

// ---------- grouped bf16 MFMA GEMM, 128x128 tile, BK=64 (R2 structure) ----------
// XCD-swizzled linear grid: 1152 blocks = 8 xcd * 9 mslot * 16 ntile.
// HW dispatches block b to XCD b%8; we map xcd -> 9 CONTIGUOUS mslots so each
// XCD's Ab slice (9*128 rows * 2KB = 2.25 MB) stays L2-resident across its 16
// n-tiles instead of every XCD streaming the whole working set.
__global__ __launch_bounds__(256) void gemm_kernel(const unsigned short* __restrict__ Ab,
                                                   const unsigned short* __restrict__ Btb,
                                                   const int* __restrict__ offs,
                                                   float* __restrict__ out) {
  __shared__ unsigned short As[128 * 64];
  __shared__ unsigned short Bs[128 * 64];
  const int t = threadIdx.x;

  const int b = blockIdx.x;
  const int xcd = b & 7;
  const int j = b >> 3;              // [0,144)
  const int mslot = xcd * 9 + (j >> 4);
  const int n0 = (j & 15) * 128;

  // slot -> (group, row tile); wave-uniform
  int prev = 0, cum = 0, row0 = 0, row_end = 0, g = 0, found = 0;
#pragma unroll
  for (int gg = 0; gg < G_NUM; ++gg) {
    int e = offs[gg];
    int tiles = (e - prev + 127) >> 7;
    if (!found && mslot < cum + tiles) {
      found = 1; g = gg; row0 = prev + (mslot - cum) * 128; row_end = e;
    }
    cum += tiles;
    prev = e;
  }
  if (!found) return;

  const int lane = t & 63;
  const int wv = t >> 6;
  const int wm = wv & 1;
  const int wn = wv >> 1;
  const int srcChunk = (t & 7) ^ ((t >> 3) & 7);  // XOR swizzle, matches frag-read side

  // hoisted global source pointers (k0-invariant) and LDS destinations
  const unsigned short* aSrc[4];
  const unsigned short* bSrc[4];
  char* aDst[4];
  char* bDst[4];
#pragma unroll
  for (int c = 0; c < 4; ++c) {
    int rl = c * 32 + (t >> 3);
    int rA = row0 + rl; if (rA > T_ROWS - 1) rA = T_ROWS - 1;  // tail clamp (store-masked)
    aSrc[c] = Ab + (size_t)rA * K_DIM + srcChunk * 8;
    bSrc[c] = Btb + ((size_t)g * N_DIM + n0 + rl) * K_DIM + srcChunk * 8;
    aDst[c] = (char*)As + c * 4096 + t * 16;
    bDst[c] = (char*)Bs + c * 4096 + t * 16;
  }

  v4f acc[4][4];
#pragma unroll
  for (int i = 0; i < 4; ++i)
#pragma unroll
    for (int j2 = 0; j2 < 4; ++j2)
#pragma unroll
      for (int r = 0; r < 4; ++r) acc[i][j2][r] = 0.0f;

  // peel: prefetch k0 = 0
#pragma unroll
  for (int c = 0; c < 4; ++c) {
    async_cp16(aSrc[c], aDst[c]);
    async_cp16(bSrc[c], bDst[c]);
  }

  for (int k0 = 0; k0 < K_DIM; k0 += 64) {
    __syncthreads();   // vmcnt(0) drain -> LDS tile ready
#pragma unroll
    for (int ks = 0; ks < 2; ++ks) {
      short8 a[4], bfr[4];
      int chBase = (lane >> 4) + ks * 4;
      int chPhys = chBase ^ (lane & 7);
#pragma unroll
      for (int im = 0; im < 4; ++im) {
        int row = wm * 64 + im * 16 + (lane & 15);
        a[im] = *(const short8*)((const char*)As + row * 128 + chPhys * 16);
      }
#pragma unroll
      for (int in = 0; in < 4; ++in) {
        int row = wn * 64 + in * 16 + (lane & 15);
        bfr[in] = *(const short8*)((const char*)Bs + row * 128 + chPhys * 16);
      }
#pragma unroll
      for (int im = 0; im < 4; ++im)
#pragma unroll
        for (int in = 0; in < 4; ++in)
          acc[im][in] = __builtin_amdgcn_mfma_f32_16x16x32_bf16(a[im], bfr[in], acc[im][in], 0, 0, 0);
    }
    if (k0 + 64 < K_DIM) {
      __syncthreads();   // all waves done reading LDS
      int koff = k0 + 64;
#pragma unroll
      for (int c = 0; c < 4; ++c) {
        async_cp16(aSrc[c] + koff, aDst[c]);
        async_cp16(bSrc[c] + koff, bDst[c]);
      }
    }
  }

  // epilogue: C/D layout col=lane&15, row=(lane>>4)*4+reg
  const int colBase = n0 + wn * 64 + (lane & 15);
  const int rowBase = row0 + wm * 64 + ((lane >> 4) << 2);
#pragma unroll
  for (int im = 0; im < 4; ++im) {
#pragma unroll
    for (int in = 0; in < 4; ++in) {
      int c = colBase + in * 16;
#pragma unroll
      for (int r = 0; r < 4; ++r) {
        int rr = rowBase + im * 16 + r;
        if (rr < row_end) out[(size_t)rr * N_DIM + c] = acc[im][in][r];
      }
    }
  }
}

// ---------- fallback (workspace too small): fp32 vector GEMM ----------
__global__ __launch_bounds__(256) void fallback_kernel(const float* __restrict__ A,
                                                       const float* __restrict__ B,
                                                       const int* __restrict__ offs,
                                                       float* __restrict__ out) {
  int r = blockIdx.y;
  int c = blockIdx.x * 256 + threadIdx.x;
  int g = 0;
#pragma unroll
  for (int i = 0; i < G_NUM; ++i) g += (offs[i] <= r);
  const float* a = A + (size_t)r * K_DIM;
  const float* b = B + (size_t)g * K_DIM * N_DIM + c;
  float s = 0.f;
  for (int k = 0; k < K_DIM; ++k) s += a[k] * b[(size_t)k * N_DIM];
  out[(size_t)r * N_DIM + c] = s;
}

extern "C" void kernel_launch(void* const* d_in, const int* in_sizes, int n_in,
                              void* d_out, int out_size, void* d_ws, size_t ws_size,
                              hipStream_t stream) {
  const float* A = (const float*)d_in[0];
  const float* B = (const float*)d_in[1];
  const int* offs = (const int*)d_in[2];
  float* out = (float*)d_out;

  size_t need = ((size_t)T_ROWS * K_DIM + (size_t)G_NUM * K_DIM * N_DIM) * 2;
  if (ws_size < need) {
    dim3 grid(N_DIM / 256, T_ROWS);
    fallback_kernel<<<grid, 256, 0, stream>>>(A, B, offs, out);
    return;
  }
  unsigned short* Ab = (unsigned short*)d_ws;
  unsigned short* Btb = Ab + (size_t)T_ROWS * K_DIM;

  conv_fused<<<CONVA_BLOCKS + CONVB_BLOCKS, 256, 0, stream>>>(A, B, Ab, Btb);
  // linear grid, XCD-swizzled inside: 8 * 9 * 16 = 1152 blocks
  gemm_kernel<<<8 * 9 * 16, 256, 0, stream>>>(Ab, Btb, offs, out);
}